// Round 1
// baseline (1312.697 us; speedup 1.0000x reference)
//
#include <hip/hip_runtime.h>
#include <hip/hip_cooperative_groups.h>
#include <math.h>

namespace cg = cooperative_groups;

#define DIM   512
#define NEL   (DIM*DIM)
#define NBLK  256
#define NTHR  256
#define PER_T (NEL/(NBLK*NTHR))   // 4 elements per thread in elementwise passes

// ---- RKF56 coefficients (rounded to f32 exactly as the f32 reference does) ----
constexpr float cA21 = 0.25f;
constexpr float cA31 = (float)(3.0/32.0),     cA32 = (float)(9.0/32.0);
constexpr float cA41 = (float)(1932.0/2197.0),cA42 = (float)(-7200.0/2197.0), cA43 = (float)(7296.0/2197.0);
constexpr float cA51 = (float)(439.0/216.0),  cA52 = -8.0f,                   cA53 = (float)(3680.0/513.0), cA54 = (float)(-845.0/4104.0);
constexpr float cA61 = (float)(-8.0/27.0),    cA62 = 2.0f,                    cA63 = (float)(-3544.0/2565.0), cA64 = (float)(1859.0/4104.0), cA65 = (float)(-11.0/40.0);
constexpr float cB1 = (float)(16.0/135.0), cB3 = (float)(6656.0/12825.0), cB4 = (float)(28561.0/56430.0), cB5 = (float)(-9.0/50.0), cB6 = (float)(2.0/55.0);
constexpr float cC1 = (float)(25.0/216.0), cC3 = (float)(1408.0/2565.0),  cC4 = (float)(2197.0/4104.0),  cC5 = -0.2f;

constexpr float TOLf = 0.01f, MIN_DTf = 0.1f, DT0f = 0.1f, MAXTf = 50.0f, VELTOLf = 0.05f;
constexpr float INVD = 1.0f/512.0f;

__device__ __forceinline__ float sech2f(float z){ float th = tanhf(z); return 1.0f - th*th; }

// y = x + dt * sum_j A[S][j] * k_j   (stage S input), computed on the fly
template<int S>
__device__ __forceinline__ float yval(int idx, const float* __restrict__ x,
  const float* __restrict__ k1, const float* __restrict__ k2,
  const float* __restrict__ k3, const float* __restrict__ k4,
  const float* __restrict__ k5, float dt)
{
  if constexpr (S == 0) { return x[idx]; }
  else {
    float a = 0.f;
    if constexpr (S == 1) a = cA21*k1[idx];
    if constexpr (S == 2) a = cA31*k1[idx] + cA32*k2[idx];
    if constexpr (S == 3) a = cA41*k1[idx] + cA42*k2[idx] + cA43*k3[idx];
    if constexpr (S == 4) a = cA51*k1[idx] + cA52*k2[idx] + cA53*k3[idx] + cA54*k4[idx];
    if constexpr (S == 5) a = cA61*k1[idx] + cA62*k2[idx] + cA63*k3[idx] + cA64*k4[idx] + cA65*k5[idx];
    return x[idx] + dt*a;
  }
}

// sbuf = sech2( y @ W + b ).  One 32x32 output tile per block.
template<int S>
__device__ void mm_fwd(const float* __restrict__ x, const float* __restrict__ W,
                       const float* __restrict__ bvec,
                       const float* __restrict__ k1, const float* __restrict__ k2,
                       const float* __restrict__ k3, const float* __restrict__ k4,
                       const float* __restrict__ k5,
                       float dt, float* __restrict__ sbuf,
                       float (&As)[32][33], float (&Bs)[32][33])
{
  const int tid = threadIdx.x;
  const int tx = tid & 31, ty = tid >> 5;
  const int tr = blockIdx.x >> 4, tc = blockIdx.x & 15;
  float acc0=0.f, acc1=0.f, acc2=0.f, acc3=0.f;
  for (int k0 = 0; k0 < DIM; k0 += 32){
    #pragma unroll
    for (int i = 0; i < 4; ++i){
      int l = tid + NTHR*i;
      int r = l >> 5, c = l & 31;
      As[r][c] = yval<S>((tr*32 + r)*DIM + (k0 + c), x, k1,k2,k3,k4,k5, dt);
      Bs[r][c] = W[(k0 + r)*DIM + (tc*32 + c)];
    }
    __syncthreads();
    #pragma unroll
    for (int kk = 0; kk < 32; ++kk){
      float bvv = Bs[kk][tx];
      acc0 = fmaf(As[ty     ][kk], bvv, acc0);
      acc1 = fmaf(As[ty +  8][kk], bvv, acc1);
      acc2 = fmaf(As[ty + 16][kk], bvv, acc2);
      acc3 = fmaf(As[ty + 24][kk], bvv, acc3);
    }
    __syncthreads();
  }
  const int col = tc*32 + tx;
  const float bb = bvec[col];
  sbuf[(tr*32 + ty     )*DIM + col] = sech2f(acc0 + bb);
  sbuf[(tr*32 + ty +  8)*DIM + col] = sech2f(acc1 + bb);
  sbuf[(tr*32 + ty + 16)*DIM + col] = sech2f(acc2 + bb);
  sbuf[(tr*32 + ty + 24)*DIM + col] = sech2f(acc3 + bb);
}

// g = sbuf @ W^T; then:
//   STOP:   v = -(2x+g)/D, per-row max|v| -> atomicMax row_max
//   S==5:   k6 = -(2y+g)/D computed locally, fused x_hi/x_lo/err; writes xh, atomicMax err
//   else:   kout = -(2y+g)/D
template<int S, bool STOP>
__device__ void mm_bwd(const float* __restrict__ x, const float* __restrict__ W,
                       const float* __restrict__ sbuf,
                       const float* __restrict__ k1, const float* __restrict__ k2,
                       const float* __restrict__ k3, const float* __restrict__ k4,
                       const float* __restrict__ k5,
                       float dt, float* __restrict__ kout,
                       float* __restrict__ xh, unsigned* __restrict__ errp,
                       unsigned* __restrict__ row_max,
                       float (&As)[32][33], float (&Bs)[32][33])
{
  const int tid = threadIdx.x;
  const int tx = tid & 31, ty = tid >> 5;
  const int tr = blockIdx.x >> 4, tc = blockIdx.x & 15;
  float acc0=0.f, acc1=0.f, acc2=0.f, acc3=0.f;
  for (int k0 = 0; k0 < DIM; k0 += 32){
    #pragma unroll
    for (int i = 0; i < 4; ++i){
      int l = tid + NTHR*i;
      int rA = l >> 5, cA = l & 31;
      As[rA][cA] = sbuf[(tr*32 + rA)*DIM + (k0 + cA)];
      int rB = l & 31, cB = l >> 5;          // coalesced load of W^T tile
      Bs[rB][cB] = W[(tc*32 + cB)*DIM + (k0 + rB)];
    }
    __syncthreads();
    #pragma unroll
    for (int kk = 0; kk < 32; ++kk){
      float bvv = Bs[kk][tx];
      acc0 = fmaf(As[ty     ][kk], bvv, acc0);
      acc1 = fmaf(As[ty +  8][kk], bvv, acc1);
      acc2 = fmaf(As[ty + 16][kk], bvv, acc2);
      acc3 = fmaf(As[ty + 24][kk], bvv, acc3);
    }
    __syncthreads();
  }
  const int col = tc*32 + tx;
  if constexpr (STOP){
    #pragma unroll
    for (int i = 0; i < 4; ++i){
      int row = tr*32 + ty + 8*i;
      int idx = row*DIM + col;
      float acc = (i==0)?acc0:(i==1)?acc1:(i==2)?acc2:acc3;
      float v = -(2.0f*x[idx] + acc) * INVD;
      As[ty + 8*i][tx] = fabsf(v);
    }
    __syncthreads();
    if (tid < 32){
      float m = 0.f;
      #pragma unroll
      for (int c = 0; c < 32; ++c) m = fmaxf(m, As[tid][c]);
      atomicMax(&row_max[tr*32 + tid], __float_as_uint(m));
    }
    __syncthreads();
  } else if constexpr (S == 5){
    float emax = 0.f;
    #pragma unroll
    for (int i = 0; i < 4; ++i){
      int row = tr*32 + ty + 8*i;
      int idx = row*DIM + col;
      float acc = (i==0)?acc0:(i==1)?acc1:(i==2)?acc2:acc3;
      float yv  = yval<5>(idx, x, k1,k2,k3,k4,k5, dt);
      float k6v = -(2.0f*yv + acc) * INVD;
      float xi = x[idx];
      float v1 = k1[idx], v3 = k3[idx], v4 = k4[idx], v5 = k5[idx];
      float hi = xi + dt*(cB1*v1 + cB3*v3 + cB4*v4 + cB5*v5 + cB6*k6v);
      float lo = xi + dt*(cC1*v1 + cC3*v3 + cC4*v4 + cC5*v5);
      xh[idx] = hi;
      emax = fmaxf(emax, fabsf(hi - lo));
    }
    __syncthreads();
    float* red = &As[0][0];
    red[tid] = emax;
    __syncthreads();
    for (int s2 = 128; s2 > 0; s2 >>= 1){
      if (tid < s2) red[tid] = fmaxf(red[tid], red[tid + s2]);
      __syncthreads();
    }
    if (tid == 0) atomicMax(errp, __float_as_uint(red[0]));
  } else {
    #pragma unroll
    for (int i = 0; i < 4; ++i){
      int row = tr*32 + ty + 8*i;
      int idx = row*DIM + col;
      float acc = (i==0)?acc0:(i==1)?acc1:(i==2)?acc2:acc3;
      float yv  = yval<S>(idx, x, k1,k2,k3,k4,k5, dt);
      kout[idx] = -(2.0f*yv + acc) * INVD;
    }
  }
}

__global__ void __launch_bounds__(NTHR, 1)
hop_kernel(const float* __restrict__ x0, const float* __restrict__ W,
           const float* __restrict__ bvec, float* __restrict__ out,
           float* __restrict__ ws)
{
  __shared__ float As[32][33];
  __shared__ float Bs[32][33];
  cg::grid_group grid = cg::this_grid();

  float* x  = ws;
  float* sb = ws + NEL;
  float* k1 = ws + 2*NEL;
  float* k2 = ws + 3*NEL;
  float* k3 = ws + 4*NEL;
  float* k4 = ws + 5*NEL;
  float* k5 = ws + 6*NEL;
  unsigned* row_max = (unsigned*)(ws + 7*NEL);
  float*    sc_t    = ws + 7*NEL + 512;
  float*    sc_dt   = ws + 7*NEL + 513;
  unsigned* sc_done = (unsigned*)(ws + 7*NEL + 514);
  unsigned* sc_err  = (unsigned*)(ws + 7*NEL + 515);

  const int tid = threadIdx.x;
  const int gid = blockIdx.x * NTHR + tid;

  // init persistent state (ws is poisoned 0xAA -- everything must be rewritten)
  #pragma unroll
  for (int i = 0; i < PER_T; ++i) x[gid + NBLK*NTHR*i] = x0[gid + NBLK*NTHR*i];
  if (blockIdx.x == 0 && tid == 0){
    __hip_atomic_store(sc_t,  0.0f, __ATOMIC_RELAXED, __HIP_MEMORY_SCOPE_AGENT);
    __hip_atomic_store(sc_dt, DT0f, __ATOMIC_RELAXED, __HIP_MEMORY_SCOPE_AGENT);
    __hip_atomic_store(sc_done, 0u, __ATOMIC_RELAXED, __HIP_MEMORY_SCOPE_AGENT);
  }
  grid.sync();

  for (int iter = 0; iter < 32; ++iter){
    unsigned done = __hip_atomic_load(sc_done, __ATOMIC_RELAXED, __HIP_MEMORY_SCOPE_AGENT);
    if (done) break;   // grid-uniform
    float dt = __hip_atomic_load(sc_dt, __ATOMIC_RELAXED, __HIP_MEMORY_SCOPE_AGENT);
    float t  = __hip_atomic_load(sc_t,  __ATOMIC_RELAXED, __HIP_MEMORY_SCOPE_AGENT);
    if (blockIdx.x == 0){
      if (tid == 0) __hip_atomic_store(sc_err, 0u, __ATOMIC_RELAXED, __HIP_MEMORY_SCOPE_AGENT);
      row_max[tid] = 0u; row_max[tid + 256] = 0u;
    }

    // ---- 6 RKF stages (stage 5 fuses x_hi/x_lo/err) ----
    mm_fwd<0>(x,W,bvec, k1,k2,k3,k4,k5, dt, sb, As,Bs);                         grid.sync();
    mm_bwd<0,false>(x,W,sb, k1,k2,k3,k4,k5, dt, k1, out, sc_err, row_max, As,Bs); grid.sync();
    mm_fwd<1>(x,W,bvec, k1,k2,k3,k4,k5, dt, sb, As,Bs);                         grid.sync();
    mm_bwd<1,false>(x,W,sb, k1,k2,k3,k4,k5, dt, k2, out, sc_err, row_max, As,Bs); grid.sync();
    mm_fwd<2>(x,W,bvec, k1,k2,k3,k4,k5, dt, sb, As,Bs);                         grid.sync();
    mm_bwd<2,false>(x,W,sb, k1,k2,k3,k4,k5, dt, k3, out, sc_err, row_max, As,Bs); grid.sync();
    mm_fwd<3>(x,W,bvec, k1,k2,k3,k4,k5, dt, sb, As,Bs);                         grid.sync();
    mm_bwd<3,false>(x,W,sb, k1,k2,k3,k4,k5, dt, k4, out, sc_err, row_max, As,Bs); grid.sync();
    mm_fwd<4>(x,W,bvec, k1,k2,k3,k4,k5, dt, sb, As,Bs);                         grid.sync();
    mm_bwd<4,false>(x,W,sb, k1,k2,k3,k4,k5, dt, k5, out, sc_err, row_max, As,Bs); grid.sync();
    mm_fwd<5>(x,W,bvec, k1,k2,k3,k4,k5, dt, sb, As,Bs);                         grid.sync();
    mm_bwd<5,false>(x,W,sb, k1,k2,k3,k4,k5, dt, nullptr, out, sc_err, row_max, As,Bs); grid.sync();

    // ---- accept / state update (uniform across grid) ----
    float err = __uint_as_float(__hip_atomic_load(sc_err, __ATOMIC_RELAXED, __HIP_MEMORY_SCOPE_AGENT));
    bool accept = (err < TOLf) || (dt <= MIN_DTf);
    if (accept){
      #pragma unroll
      for (int i = 0; i < PER_T; ++i){ int idx = gid + NBLK*NTHR*i; x[idx] = out[idx]; }
    }
    grid.sync();

    // ---- stop condition: pvf(x2), per-row max |v|, mean over rows ----
    mm_fwd<0>(x,W,bvec, k1,k2,k3,k4,k5, dt, sb, As,Bs);                          grid.sync();
    mm_bwd<0,true>(x,W,sb, k1,k2,k3,k4,k5, dt, nullptr, out, sc_err, row_max, As,Bs); grid.sync();

    if (blockIdx.x == 0){
      float* red = &As[0][0];
      red[tid] = __uint_as_float(row_max[tid]) + __uint_as_float(row_max[tid + 256]);
      __syncthreads();
      for (int s2 = 128; s2 > 0; s2 >>= 1){
        if (tid < s2) red[tid] += red[tid + s2];
        __syncthreads();
      }
      if (tid == 0){
        float vel = red[0] * (1.0f/512.0f);
        float t2 = accept ? (t + dt) : t;
        float factor = 0.9f * powf(TOLf / (err + 1e-12f), 0.2f);
        factor = fminf(fmaxf(factor, 0.2f), 2.0f);
        float dtn = fmaxf(dt * factor, MIN_DTf);
        unsigned dn = ((t2 > MAXTf) || (vel < VELTOLf)) ? 1u : 0u;
        __hip_atomic_store(sc_t,  t2,  __ATOMIC_RELAXED, __HIP_MEMORY_SCOPE_AGENT);
        __hip_atomic_store(sc_dt, dtn, __ATOMIC_RELAXED, __HIP_MEMORY_SCOPE_AGENT);
        __hip_atomic_store(sc_done, dn, __ATOMIC_RELAXED, __HIP_MEMORY_SCOPE_AGENT);
      }
    }
    grid.sync();
  }

  // final output
  #pragma unroll
  for (int i = 0; i < PER_T; ++i){ int idx = gid + NBLK*NTHR*i; out[idx] = x[idx]; }
}

extern "C" void kernel_launch(void* const* d_in, const int* in_sizes, int n_in,
                              void* d_out, int out_size, void* d_ws, size_t ws_size,
                              hipStream_t stream)
{
  const float* x0 = (const float*)d_in[0];
  const float* W  = (const float*)d_in[1];
  const float* bv = (const float*)d_in[2];
  float* out = (float*)d_out;
  float* ws  = (float*)d_ws;
  void* args[] = { (void*)&x0, (void*)&W, (void*)&bv, (void*)&out, (void*)&ws };
  (void)in_sizes; (void)n_in; (void)out_size; (void)ws_size;
  hipLaunchCooperativeKernel((void*)hop_kernel, dim3(NBLK), dim3(NTHR), args, 0, stream);
}

// Round 2
// 610.072 us; speedup vs baseline: 2.1517x; 2.1517x over previous
//
#include <hip/hip_runtime.h>
#include <hip/hip_cooperative_groups.h>
#include <math.h>

namespace cg = cooperative_groups;

#define DIM  512
#define NBLK 256
#define NTHR 256

// ---- RKF56 coefficients ----
constexpr float cA21 = 0.25f;
constexpr float cA31 = (float)(3.0/32.0),     cA32 = (float)(9.0/32.0);
constexpr float cA41 = (float)(1932.0/2197.0),cA42 = (float)(-7200.0/2197.0), cA43 = (float)(7296.0/2197.0);
constexpr float cA51 = (float)(439.0/216.0),  cA52 = -8.0f,                   cA53 = (float)(3680.0/513.0), cA54 = (float)(-845.0/4104.0);
constexpr float cA61 = (float)(-8.0/27.0),    cA62 = 2.0f,                    cA63 = (float)(-3544.0/2565.0), cA64 = (float)(1859.0/4104.0), cA65 = (float)(-11.0/40.0);
constexpr float cB1 = (float)(16.0/135.0), cB3 = (float)(6656.0/12825.0), cB4 = (float)(28561.0/56430.0), cB5 = (float)(-9.0/50.0), cB6 = (float)(2.0/55.0);
constexpr float cC1 = (float)(25.0/216.0), cC3 = (float)(1408.0/2565.0),  cC4 = (float)(2197.0/4104.0),  cC5 = -0.2f;

constexpr float TOLf = 0.01f, MIN_DTf = 0.1f, DT0f = 0.1f, MAXTf = 50.0f, VELTOLf = 0.05f;
constexpr float INVD = 1.0f/512.0f;

__device__ __forceinline__ unsigned short f2bf(float f){
  unsigned u = __float_as_uint(f);
  unsigned r = (u + 0x7fffu + ((u >> 16) & 1u)) >> 16;   // RNE
  return (unsigned short)r;
}

// custom scalar barrier: one slot per use (zeroed by host memset), no bulk flush needed
__device__ __forceinline__ void gbar(unsigned* ctr, int tid){
  __syncthreads();
  if (tid == 0){
    __hip_atomic_fetch_add(ctr, 1u, __ATOMIC_RELEASE, __HIP_MEMORY_SCOPE_AGENT);
    unsigned v;
    do {
      __builtin_amdgcn_s_sleep(2);
      v = __hip_atomic_load(ctr, __ATOMIC_RELAXED, __HIP_MEMORY_SCOPE_AGENT);
    } while (v < NBLK);
    (void)__hip_atomic_load(ctr, __ATOMIC_ACQUIRE, __HIP_MEMORY_SCOPE_AGENT);
  }
  __syncthreads();
}

// acc[0..3] = sum_k lds[r][k] * bf16row(Wh, k)[c0..c0+3]
__device__ __forceinline__ void mm_half(const unsigned short* __restrict__ Wh,
                                        const float (&lds)[2][DIM],
                                        int r, int c0, float acc[4])
{
  float a0=0.f, a1=0.f, a2=0.f, a3=0.f;
  const unsigned short* p = Wh + c0;
  #pragma unroll 16
  for (int k = 0; k < DIM; ++k){
    float yv = lds[r][k];                          // LDS broadcast (uniform per wave)
    uint2 w = *reinterpret_cast<const uint2*>(p + (size_t)k*DIM);   // 4 bf16, 8B coalesced
    a0 = fmaf(yv, __uint_as_float(w.x << 16),         a0);
    a1 = fmaf(yv, __uint_as_float(w.x & 0xffff0000u), a1);
    a2 = fmaf(yv, __uint_as_float(w.y << 16),         a2);
    a3 = fmaf(yv, __uint_as_float(w.y & 0xffff0000u), a3);
  }
  acc[0]=a0; acc[1]=a1; acc[2]=a2; acc[3]=a3;
}

__global__ void __launch_bounds__(NTHR, 1)
hop_kernel(const float* __restrict__ x0, const float* __restrict__ W,
           const float* __restrict__ bvec, float* __restrict__ out,
           unsigned char* __restrict__ ws)
{
  cg::grid_group grid = cg::this_grid();

  unsigned*           bar  = (unsigned*)ws;                       // slots [0..95]
  unsigned*           errs = (unsigned*)(ws) + 96;                // errs[32]
  unsigned long long* vels = (unsigned long long*)(ws + 512);     // vels[32]
  unsigned short*     Wb   = (unsigned short*)(ws + 4096);        // 512x512 bf16
  unsigned short*     WTb  = Wb + DIM*DIM;                        // transposed

  const int tid  = threadIdx.x;
  const int b    = blockIdx.x;
  const int r    = tid >> 7;          // 0/1 : which of the block's two rows
  const int c0   = (tid & 127) << 2;  // 4 contiguous cols per thread
  const int grow = 2*b + r;           // global batch row

  __shared__ float ylds[2][DIM];
  __shared__ float slds[2][DIM];
  __shared__ float red[NTHR];
  __shared__ float bcast[4];

  // ---- one-time: convert W -> bf16 (linear + transposed) ----
  {
    int e0 = (b*NTHR + tid) * 4;                  // flat element index into W
    const float4 w4 = *reinterpret_cast<const float4*>(W + e0);
    int k = e0 >> 9, j = e0 & 511;
    unsigned short h0 = f2bf(w4.x), h1 = f2bf(w4.y), h2 = f2bf(w4.z), h3 = f2bf(w4.w);
    ushort4 hv; hv.x=h0; hv.y=h1; hv.z=h2; hv.w=h3;
    *reinterpret_cast<ushort4*>(Wb + e0) = hv;    // coalesced
    WTb[(size_t)(j+0)*DIM + k] = h0;              // scattered, one-time
    WTb[(size_t)(j+1)*DIM + k] = h1;
    WTb[(size_t)(j+2)*DIM + k] = h2;
    WTb[(size_t)(j+3)*DIM + k] = h3;
  }

  // per-thread persistent state (4 elements of one batch row)
  float x[4];
  { float4 xx = *reinterpret_cast<const float4*>(x0 + (size_t)grow*DIM + c0);
    x[0]=xx.x; x[1]=xx.y; x[2]=xx.z; x[3]=xx.w; }
  float bv[4];
  { float4 b4 = *reinterpret_cast<const float4*>(bvec + c0);
    bv[0]=b4.x; bv[1]=b4.y; bv[2]=b4.z; bv[3]=b4.w; }

  grid.sync();   // publish Wb/WTb across XCDs (full release/acquire, once)

  float t = 0.f, dt = DT0f;
  float k1[4],k2[4],k3[4],k4[4],k5[4],xhi[4],acc[4];

  auto set_y = [&](float y0, float y1, float y2, float y3){
    ylds[r][c0+0]=y0; ylds[r][c0+1]=y1; ylds[r][c0+2]=y2; ylds[r][c0+3]=y3;
    __syncthreads();
  };
  auto run_fwd = [&](){
    mm_half(Wb, ylds, r, c0, acc);
    #pragma unroll
    for (int i = 0; i < 4; ++i){
      float th = tanhf(acc[i] + bv[i]);
      slds[r][c0+i] = 1.f - th*th;
    }
    __syncthreads();
  };
  auto run_bwd = [&](float kout[4]){
    mm_half(WTb, slds, r, c0, acc);
    #pragma unroll
    for (int i = 0; i < 4; ++i)
      kout[i] = -(2.f*ylds[r][c0+i] + acc[i]) * INVD;
    __syncthreads();
  };

  for (int iter = 0; iter < 32; ++iter){
    // ---- 5 full stages ----
    set_y(x[0], x[1], x[2], x[3]);
    run_fwd(); run_bwd(k1);
    set_y(x[0]+dt*(cA21*k1[0]), x[1]+dt*(cA21*k1[1]), x[2]+dt*(cA21*k1[2]), x[3]+dt*(cA21*k1[3]));
    run_fwd(); run_bwd(k2);
    set_y(x[0]+dt*(cA31*k1[0]+cA32*k2[0]), x[1]+dt*(cA31*k1[1]+cA32*k2[1]),
          x[2]+dt*(cA31*k1[2]+cA32*k2[2]), x[3]+dt*(cA31*k1[3]+cA32*k2[3]));
    run_fwd(); run_bwd(k3);
    set_y(x[0]+dt*(cA41*k1[0]+cA42*k2[0]+cA43*k3[0]), x[1]+dt*(cA41*k1[1]+cA42*k2[1]+cA43*k3[1]),
          x[2]+dt*(cA41*k1[2]+cA42*k2[2]+cA43*k3[2]), x[3]+dt*(cA41*k1[3]+cA42*k2[3]+cA43*k3[3]));
    run_fwd(); run_bwd(k4);
    set_y(x[0]+dt*(cA51*k1[0]+cA52*k2[0]+cA53*k3[0]+cA54*k4[0]),
          x[1]+dt*(cA51*k1[1]+cA52*k2[1]+cA53*k3[1]+cA54*k4[1]),
          x[2]+dt*(cA51*k1[2]+cA52*k2[2]+cA53*k3[2]+cA54*k4[2]),
          x[3]+dt*(cA51*k1[3]+cA52*k2[3]+cA53*k3[3]+cA54*k4[3]));
    run_fwd(); run_bwd(k5);

    // ---- stage 6: fused k6 / x_hi / x_lo / err ----
    set_y(x[0]+dt*(cA61*k1[0]+cA62*k2[0]+cA63*k3[0]+cA64*k4[0]+cA65*k5[0]),
          x[1]+dt*(cA61*k1[1]+cA62*k2[1]+cA63*k3[1]+cA64*k4[1]+cA65*k5[1]),
          x[2]+dt*(cA61*k1[2]+cA62*k2[2]+cA63*k3[2]+cA64*k4[2]+cA65*k5[2]),
          x[3]+dt*(cA61*k1[3]+cA62*k2[3]+cA63*k3[3]+cA64*k4[3]+cA65*k5[3]));
    run_fwd();
    mm_half(WTb, slds, r, c0, acc);
    float emax = 0.f;
    #pragma unroll
    for (int i = 0; i < 4; ++i){
      float yv = ylds[r][c0+i];
      float k6 = -(2.f*yv + acc[i]) * INVD;
      float hi = x[i] + dt*(cB1*k1[i] + cB3*k3[i] + cB4*k4[i] + cB5*k5[i] + cB6*k6);
      float lo = x[i] + dt*(cC1*k1[i] + cC3*k3[i] + cC4*k4[i] + cC5*k5[i]);
      xhi[i] = hi;
      emax = fmaxf(emax, fabsf(hi - lo));
    }
    __syncthreads();
    red[tid] = emax; __syncthreads();
    for (int s = 128; s > 0; s >>= 1){
      if (tid < s) red[tid] = fmaxf(red[tid], red[tid + s]);
      __syncthreads();
    }
    if (tid == 0) atomicMax(&errs[iter], __float_as_uint(red[0]));

    gbar(&bar[2*iter], tid);                       // scalar barrier #1
    if (tid == 0)
      bcast[0] = __uint_as_float(__hip_atomic_load(&errs[iter], __ATOMIC_RELAXED, __HIP_MEMORY_SCOPE_AGENT));
    __syncthreads();
    const float err = bcast[0];
    const bool accept = (err < TOLf) || (dt <= MIN_DTf);
    if (accept){ x[0]=xhi[0]; x[1]=xhi[1]; x[2]=xhi[2]; x[3]=xhi[3]; }

    // ---- stop condition: pvf(x2), per-row max, grid mean ----
    set_y(x[0], x[1], x[2], x[3]);
    run_fwd();
    mm_half(WTb, slds, r, c0, acc);
    float vmax = 0.f;
    #pragma unroll
    for (int i = 0; i < 4; ++i)
      vmax = fmaxf(vmax, fabsf(-(2.f*x[i] + acc[i]) * INVD));
    __syncthreads();
    red[tid] = vmax; __syncthreads();
    for (int s = 64; s > 0; s >>= 1){               // reduce within each 128-thread row group
      if ((tid & 127) < s) red[tid] = fmaxf(red[tid], red[tid + s]);
      __syncthreads();
    }
    if (tid == 0){
      double rsum = (double)red[0] + (double)red[128];
      unsigned long long fx = (unsigned long long)(rsum * 4294967296.0);  // 2^32 fixed-point (order-independent sum)
      atomicAdd(&vels[iter], fx);
    }

    gbar(&bar[2*iter+1], tid);                     // scalar barrier #2
    if (tid == 0){
      unsigned long long sv = __hip_atomic_load(&vels[iter], __ATOMIC_RELAXED, __HIP_MEMORY_SCOPE_AGENT);
      float vel = (float)((double)sv * (1.0/4294967296.0) / 512.0);
      float t2  = accept ? (t + dt) : t;
      float factor = 0.9f * powf(TOLf / (err + 1e-12f), 0.2f);
      factor = fminf(fmaxf(factor, 0.2f), 2.0f);
      float dtn = fmaxf(dt * factor, MIN_DTf);
      bcast[0] = t2; bcast[1] = dtn;
      bcast[2] = ((t2 > MAXTf) || (vel < VELTOLf)) ? 1.f : 0.f;
    }
    __syncthreads();
    t = bcast[0]; dt = bcast[1];
    if (bcast[2] != 0.f) break;                    // uniform across grid
  }

  float4 o; o.x=x[0]; o.y=x[1]; o.z=x[2]; o.w=x[3];
  *reinterpret_cast<float4*>(out + (size_t)grow*DIM + c0) = o;
}

extern "C" void kernel_launch(void* const* d_in, const int* in_sizes, int n_in,
                              void* d_out, int out_size, void* d_ws, size_t ws_size,
                              hipStream_t stream)
{
  const float* x0 = (const float*)d_in[0];
  const float* W  = (const float*)d_in[1];
  const float* bv = (const float*)d_in[2];
  float* out = (float*)d_out;
  unsigned char* ws = (unsigned char*)d_ws;

  // zero the barrier/scalar region (slots are one-shot per launch)
  hipMemsetAsync(ws, 0, 4096, stream);

  void* args[] = { (void*)&x0, (void*)&W, (void*)&bv, (void*)&out, (void*)&ws };
  (void)in_sizes; (void)n_in; (void)out_size; (void)ws_size;
  hipLaunchCooperativeKernel((void*)hop_kernel, dim3(NBLK), dim3(NTHR), args, 0, stream);
}

// Round 3
// 443.180 us; speedup vs baseline: 2.9620x; 1.3766x over previous
//
#include <hip/hip_runtime.h>
#include <hip/hip_cooperative_groups.h>
#include <hip/hip_fp16.h>
#include <math.h>

namespace cg = cooperative_groups;

#define DIM   512
#define NBLK  64
#define NTHR  1024
#define NROW  8              // batch rows per block
#define KP    (DIM/2)        // 256 packed k-pairs

typedef _Float16 h2 __attribute__((ext_vector_type(2)));

#if __has_builtin(__builtin_amdgcn_fdot2)
__device__ __forceinline__ float dot2f(h2 a, h2 b, float c){
  return __builtin_amdgcn_fdot2(a, b, c, false);
}
#else
__device__ __forceinline__ float dot2f(h2 a, h2 b, float c){
  return fmaf((float)a[0], (float)b[0], fmaf((float)a[1], (float)b[1], c));
}
#endif

// ---- RKF56 coefficients ----
constexpr float cA21 = 0.25f;
constexpr float cA31 = (float)(3.0/32.0),     cA32 = (float)(9.0/32.0);
constexpr float cA41 = (float)(1932.0/2197.0),cA42 = (float)(-7200.0/2197.0), cA43 = (float)(7296.0/2197.0);
constexpr float cA51 = (float)(439.0/216.0),  cA52 = -8.0f,                   cA53 = (float)(3680.0/513.0), cA54 = (float)(-845.0/4104.0);
constexpr float cA61 = (float)(-8.0/27.0),    cA62 = 2.0f,                    cA63 = (float)(-3544.0/2565.0), cA64 = (float)(1859.0/4104.0), cA65 = (float)(-11.0/40.0);
constexpr float cB1 = (float)(16.0/135.0), cB3 = (float)(6656.0/12825.0), cB4 = (float)(28561.0/56430.0), cB5 = (float)(-9.0/50.0), cB6 = (float)(2.0/55.0);
constexpr float cC1 = (float)(25.0/216.0), cC3 = (float)(1408.0/2565.0),  cC4 = (float)(2197.0/4104.0),  cC5 = -0.2f;

constexpr float TOLf = 0.01f, MIN_DTf = 0.1f, DT0f = 0.1f, MAXTf = 50.0f, VELTOLf = 0.05f;
constexpr float INVD = 1.0f/512.0f;

__device__ __forceinline__ unsigned packh(float a, float b){
  unsigned short lo = __half_as_ushort(__float2half(a));   // RNE
  unsigned short hi = __half_as_ushort(__float2half(b));
  return (unsigned)lo | ((unsigned)hi << 16);
}

// scalar grid barrier: one slot per use (zeroed by host memset), no bulk L2 flush
__device__ __forceinline__ void gbar(unsigned* ctr, int tid){
  __syncthreads();
  if (tid == 0){
    __hip_atomic_fetch_add(ctr, 1u, __ATOMIC_RELEASE, __HIP_MEMORY_SCOPE_AGENT);
    unsigned v;
    do {
      __builtin_amdgcn_s_sleep(2);
      v = __hip_atomic_load(ctr, __ATOMIC_RELAXED, __HIP_MEMORY_SCOPE_AGENT);
    } while (v < NBLK);
    (void)__hip_atomic_load(ctr, __ATOMIC_ACQUIRE, __HIP_MEMORY_SCOPE_AGENT);
  }
  __syncthreads();
}

__global__ void __launch_bounds__(NTHR, 1)
hop_kernel(const float* __restrict__ x0, const float* __restrict__ W,
           const float* __restrict__ bvec, float* __restrict__ out,
           unsigned char* __restrict__ ws)
{
  cg::grid_group grid = cg::this_grid();

  unsigned*           bar  = (unsigned*)ws;                    // slots [0..95]
  unsigned*           errs = (unsigned*)ws + 96;               // errs[32]
  unsigned long long* vels = (unsigned long long*)(ws + 512);  // vels[32]
  unsigned*           Wpk  = (unsigned*)(ws + 4096);           // [KP][DIM] f16x2
  unsigned*           WTpk = Wpk + KP*DIM;                     // transposed

  const int tid  = threadIdx.x;
  const int b    = blockIdx.x;
  const int r    = tid >> 7;           // 0..7  : row within block
  const int c0   = (tid & 127) << 2;   // 4 contiguous cols per thread
  const int wid  = tid >> 6;           // wave id 0..15
  const int lane = tid & 63;
  const int grow = b*NROW + r;

  __shared__ unsigned pkY[NROW][KP];   // 8 KB packed y  (f16x2)
  __shared__ unsigned pkS[NROW][KP];   // 8 KB packed sech2
  __shared__ float red[32];
  __shared__ float bcast[4];

  // ---- one-time: W -> packed f16 (normal + transposed) ----
  #pragma unroll
  for (int rep = 0; rep < 2; ++rep){
    int e  = b*NTHR + tid + rep*(NBLK*NTHR);    // [0, 131072)
    int kp = e >> 9, c = e & 511;
    Wpk[e]  = packh(W[(2*kp)*DIM + c], W[(2*kp+1)*DIM + c]);        // coalesced reads
    float2 wt = *reinterpret_cast<const float2*>(W + (size_t)c*DIM + 2*kp);
    WTpk[e] = packh(wt.x, wt.y);                                     // 8B/lane, one-time
  }

  // per-thread persistent state: 4 elements of one batch row
  float x[4], bv[4];
  { float4 xx = *reinterpret_cast<const float4*>(x0 + (size_t)grow*DIM + c0);
    x[0]=xx.x; x[1]=xx.y; x[2]=xx.z; x[3]=xx.w; }
  { float4 b4 = *reinterpret_cast<const float4*>(bvec + c0);
    bv[0]=b4.x; bv[1]=b4.y; bv[2]=b4.z; bv[3]=b4.w; }

  grid.sync();   // publish Wpk/WTpk across XCDs (once)

  float t = 0.f, dt = DT0f;
  float k1[4],k2[4],k3[4],k4[4],k5[4],xhi[4],yreg[4];

  // acc[0..3] += sum over k of pk-row  dot  Wp cols c0..c0+3
  auto dotp = [&](const unsigned* __restrict__ Wp, const unsigned (&pk)[NROW][KP],
                  float acc[4]){
    float a0=0.f,a1=0.f,a2=0.f,a3=0.f;
    const unsigned* p = Wp + c0;
    #pragma unroll 8
    for (int kp = 0; kp < KP; ++kp){
      h2 yv = __builtin_bit_cast(h2, pk[r][kp]);            // LDS broadcast
      uint4 w = *reinterpret_cast<const uint4*>(p);          // 16B coalesced
      a0 = dot2f(yv, __builtin_bit_cast(h2, w.x), a0);
      a1 = dot2f(yv, __builtin_bit_cast(h2, w.y), a1);
      a2 = dot2f(yv, __builtin_bit_cast(h2, w.z), a2);
      a3 = dot2f(yv, __builtin_bit_cast(h2, w.w), a3);
      p += DIM;
    }
    acc[0]=a0; acc[1]=a1; acc[2]=a2; acc[3]=a3;
  };

  auto set_y = [&](float y0, float y1, float y2, float y3){
    yreg[0]=y0; yreg[1]=y1; yreg[2]=y2; yreg[3]=y3;
    pkY[r][(c0>>1)  ] = packh(y0, y1);
    pkY[r][(c0>>1)+1] = packh(y2, y3);
    __syncthreads();
  };
  auto run_fwd = [&](){
    float acc[4]; dotp(Wpk, pkY, acc);
    float s[4];
    #pragma unroll
    for (int i = 0; i < 4; ++i){
      float th = tanhf(acc[i] + bv[i]);
      s[i] = 1.f - th*th;
    }
    pkS[r][(c0>>1)  ] = packh(s[0], s[1]);
    pkS[r][(c0>>1)+1] = packh(s[2], s[3]);
    __syncthreads();
  };
  auto run_bwd = [&](float kout[4]){
    float acc[4]; dotp(WTpk, pkS, acc);
    #pragma unroll
    for (int i = 0; i < 4; ++i)
      kout[i] = -(2.f*yreg[i] + acc[i]) * INVD;
  };

  for (int iter = 0; iter < 32; ++iter){
    // ---- 5 full stages ----
    set_y(x[0], x[1], x[2], x[3]);
    run_fwd(); run_bwd(k1);
    set_y(x[0]+dt*(cA21*k1[0]), x[1]+dt*(cA21*k1[1]),
          x[2]+dt*(cA21*k1[2]), x[3]+dt*(cA21*k1[3]));
    run_fwd(); run_bwd(k2);
    set_y(x[0]+dt*(cA31*k1[0]+cA32*k2[0]), x[1]+dt*(cA31*k1[1]+cA32*k2[1]),
          x[2]+dt*(cA31*k1[2]+cA32*k2[2]), x[3]+dt*(cA31*k1[3]+cA32*k2[3]));
    run_fwd(); run_bwd(k3);
    set_y(x[0]+dt*(cA41*k1[0]+cA42*k2[0]+cA43*k3[0]), x[1]+dt*(cA41*k1[1]+cA42*k2[1]+cA43*k3[1]),
          x[2]+dt*(cA41*k1[2]+cA42*k2[2]+cA43*k3[2]), x[3]+dt*(cA41*k1[3]+cA42*k2[3]+cA43*k3[3]));
    run_fwd(); run_bwd(k4);
    set_y(x[0]+dt*(cA51*k1[0]+cA52*k2[0]+cA53*k3[0]+cA54*k4[0]),
          x[1]+dt*(cA51*k1[1]+cA52*k2[1]+cA53*k3[1]+cA54*k4[1]),
          x[2]+dt*(cA51*k1[2]+cA52*k2[2]+cA53*k3[2]+cA54*k4[2]),
          x[3]+dt*(cA51*k1[3]+cA52*k2[3]+cA53*k3[3]+cA54*k4[3]));
    run_fwd(); run_bwd(k5);

    // ---- stage 6 fused: k6 / x_hi / x_lo / err ----
    set_y(x[0]+dt*(cA61*k1[0]+cA62*k2[0]+cA63*k3[0]+cA64*k4[0]+cA65*k5[0]),
          x[1]+dt*(cA61*k1[1]+cA62*k2[1]+cA63*k3[1]+cA64*k4[1]+cA65*k5[1]),
          x[2]+dt*(cA61*k1[2]+cA62*k2[2]+cA63*k3[2]+cA64*k4[2]+cA65*k5[2]),
          x[3]+dt*(cA61*k1[3]+cA62*k2[3]+cA63*k3[3]+cA64*k4[3]+cA65*k5[3]));
    run_fwd();
    {
      float acc[4]; dotp(WTpk, pkS, acc);
      float emax = 0.f;
      #pragma unroll
      for (int i = 0; i < 4; ++i){
        float k6 = -(2.f*yreg[i] + acc[i]) * INVD;
        float hi = x[i] + dt*(cB1*k1[i] + cB3*k3[i] + cB4*k4[i] + cB5*k5[i] + cB6*k6);
        float lo = x[i] + dt*(cC1*k1[i] + cC3*k3[i] + cC4*k4[i] + cC5*k5[i]);
        xhi[i] = hi;
        emax = fmaxf(emax, fabsf(hi - lo));
      }
      // wave-level max, then cross-wave
      #pragma unroll
      for (int s = 32; s > 0; s >>= 1) emax = fmaxf(emax, __shfl_xor(emax, s, 64));
      if (lane == 0) red[wid] = emax;
      __syncthreads();
      if (tid == 0){
        float m = red[0];
        #pragma unroll
        for (int wv = 1; wv < 16; ++wv) m = fmaxf(m, red[wv]);
        atomicMax(&errs[iter], __float_as_uint(m));
      }
    }

    gbar(&bar[2*iter], tid);                        // grid barrier #1
    if (tid == 0)
      bcast[0] = __uint_as_float(__hip_atomic_load(&errs[iter], __ATOMIC_RELAXED, __HIP_MEMORY_SCOPE_AGENT));
    __syncthreads();
    const float err = bcast[0];
    const bool accept = (err < TOLf) || (dt <= MIN_DTf);
    if (accept){ x[0]=xhi[0]; x[1]=xhi[1]; x[2]=xhi[2]; x[3]=xhi[3]; }

    // ---- stop condition: pvf(x2), per-row max |v|, grid mean over rows ----
    set_y(x[0], x[1], x[2], x[3]);
    run_fwd();
    {
      float acc[4]; dotp(WTpk, pkS, acc);
      float vmax = 0.f;
      #pragma unroll
      for (int i = 0; i < 4; ++i)
        vmax = fmaxf(vmax, fabsf(-(2.f*x[i] + acc[i]) * INVD));
      #pragma unroll
      for (int s = 32; s > 0; s >>= 1) vmax = fmaxf(vmax, __shfl_xor(vmax, s, 64));
      if (lane == 0) red[wid] = vmax;               // 2 waves per row
      __syncthreads();
      if (tid == 0){
        double rsum = 0.0;
        #pragma unroll
        for (int rr = 0; rr < NROW; ++rr)
          rsum += (double)fmaxf(red[2*rr], red[2*rr+1]);
        unsigned long long fx = (unsigned long long)(rsum * 4294967296.0);
        atomicAdd(&vels[iter], fx);
      }
    }

    gbar(&bar[2*iter+1], tid);                      // grid barrier #2
    if (tid == 0){
      unsigned long long sv = __hip_atomic_load(&vels[iter], __ATOMIC_RELAXED, __HIP_MEMORY_SCOPE_AGENT);
      float vel = (float)((double)sv * (1.0/4294967296.0) / 512.0);
      float t2  = accept ? (t + dt) : t;
      float factor = 0.9f * powf(TOLf / (err + 1e-12f), 0.2f);
      factor = fminf(fmaxf(factor, 0.2f), 2.0f);
      float dtn = fmaxf(dt * factor, MIN_DTf);
      bcast[0] = t2; bcast[1] = dtn;
      bcast[2] = ((t2 > MAXTf) || (vel < VELTOLf)) ? 1.f : 0.f;
    }
    __syncthreads();
    t = bcast[0]; dt = bcast[1];
    if (bcast[2] != 0.f) break;                     // uniform across grid
  }

  float4 o; o.x=x[0]; o.y=x[1]; o.z=x[2]; o.w=x[3];
  *reinterpret_cast<float4*>(out + (size_t)grow*DIM + c0) = o;
}

extern "C" void kernel_launch(void* const* d_in, const int* in_sizes, int n_in,
                              void* d_out, int out_size, void* d_ws, size_t ws_size,
                              hipStream_t stream)
{
  const float* x0 = (const float*)d_in[0];
  const float* W  = (const float*)d_in[1];
  const float* bv = (const float*)d_in[2];
  float* out = (float*)d_out;
  unsigned char* ws = (unsigned char*)d_ws;

  hipMemsetAsync(ws, 0, 4096, stream);   // barrier slots + errs + vels

  void* args[] = { (void*)&x0, (void*)&W, (void*)&bv, (void*)&out, (void*)&ws };
  (void)in_sizes; (void)n_in; (void)out_size; (void)ws_size;
  hipLaunchCooperativeKernel((void*)hop_kernel, dim3(NBLK), dim3(NTHR), args, 0, stream);
}

// Round 4
// 144.937 us; speedup vs baseline: 9.0570x; 3.0577x over previous
//
#include <hip/hip_runtime.h>
#include <hip/hip_cooperative_groups.h>
#include <hip/hip_fp16.h>
#include <math.h>

namespace cg = cooperative_groups;

#define DIM   512
#define NBLK  128
#define NTHR  1024
#define NROW  4              // batch rows per block (128*4 = 512)
#define KP    256            // packed k-pairs
#define KHALF 128            // kp per k-half thread

typedef _Float16 h2 __attribute__((ext_vector_type(2)));

#if __has_builtin(__builtin_amdgcn_fdot2)
__device__ __forceinline__ float dot2f(unsigned a, unsigned b, float c){
  return __builtin_amdgcn_fdot2(__builtin_bit_cast(h2, a), __builtin_bit_cast(h2, b), c, false);
}
#else
__device__ __forceinline__ float dot2f(unsigned au, unsigned bu, float c){
  h2 a = __builtin_bit_cast(h2, au), b = __builtin_bit_cast(h2, bu);
  return fmaf((float)a[0], (float)b[0], fmaf((float)a[1], (float)b[1], c));
}
#endif

// ---- RKF56 coefficients ----
constexpr float cA21 = 0.25f;
constexpr float cA31 = (float)(3.0/32.0),     cA32 = (float)(9.0/32.0);
constexpr float cA41 = (float)(1932.0/2197.0),cA42 = (float)(-7200.0/2197.0), cA43 = (float)(7296.0/2197.0);
constexpr float cA51 = (float)(439.0/216.0),  cA52 = -8.0f,                   cA53 = (float)(3680.0/513.0), cA54 = (float)(-845.0/4104.0);
constexpr float cA61 = (float)(-8.0/27.0),    cA62 = 2.0f,                    cA63 = (float)(-3544.0/2565.0), cA64 = (float)(1859.0/4104.0), cA65 = (float)(-11.0/40.0);
constexpr float cB1 = (float)(16.0/135.0), cB3 = (float)(6656.0/12825.0), cB4 = (float)(28561.0/56430.0), cB5 = (float)(-9.0/50.0), cB6 = (float)(2.0/55.0);
constexpr float cC1 = (float)(25.0/216.0), cC3 = (float)(1408.0/2565.0),  cC4 = (float)(2197.0/4104.0),  cC5 = -0.2f;

constexpr float TOLf = 0.01f, MIN_DTf = 0.1f, DT0f = 0.1f, MAXTf = 50.0f, VELTOLf = 0.05f;
constexpr float INVD = 1.0f/512.0f;

__device__ __forceinline__ unsigned packh(float a, float b){
  unsigned short lo = __half_as_ushort(__float2half(a));   // RNE
  unsigned short hi = __half_as_ushort(__float2half(b));
  return (unsigned)lo | ((unsigned)hi << 16);
}

// scalar grid barrier: one slot per use (zeroed by host memset), no bulk L2 flush
__device__ __forceinline__ void gbar(unsigned* ctr, int tid){
  __syncthreads();
  if (tid == 0){
    __hip_atomic_fetch_add(ctr, 1u, __ATOMIC_RELEASE, __HIP_MEMORY_SCOPE_AGENT);
    unsigned v;
    do {
      __builtin_amdgcn_s_sleep(2);
      v = __hip_atomic_load(ctr, __ATOMIC_RELAXED, __HIP_MEMORY_SCOPE_AGENT);
    } while (v < NBLK);
    (void)__hip_atomic_load(ctr, __ATOMIC_ACQUIRE, __HIP_MEMORY_SCOPE_AGENT);
  }
  __syncthreads();
}

__global__ void __launch_bounds__(NTHR, 1)
hop_kernel(const float* __restrict__ x0, const float* __restrict__ W,
           const float* __restrict__ bvec, float* __restrict__ out,
           unsigned char* __restrict__ ws)
{
  cg::grid_group grid = cg::this_grid();

  unsigned*           bar  = (unsigned*)ws;                    // 96 slots
  unsigned*           errs = (unsigned*)(ws + 384);            // errs[32]
  unsigned long long* vels = (unsigned long long*)(ws + 512);  // vels[32]
  unsigned*           Wq   = (unsigned*)(ws + 4096);           // interleaved f16x2, 512 KB
  unsigned*           WTq  = Wq + KP*DIM;                      // transposed, 512 KB

  const int tid  = threadIdx.x;
  const int b    = blockIdx.x;
  const int wid  = tid >> 6;
  const int lane = tid & 63;

  // matmul-layout coords: one column, one k-half
  const int mc = tid & 511;            // column 0..511
  const int mh = tid >> 9;             // k-half 0/1
  // pointwise-layout coords: one row, one column-pair
  const int pr   = tid >> 8;           // row 0..3
  const int pc   = tid & 255;          // col-pair index == kp index it owns
  const int colA = pc << 1;
  const int grow = b*NROW + pr;        // global batch row

  __shared__ __align__(16) unsigned pkY[KP*NROW];  // y  packed f16x2, [kp][row], 4 KB
  __shared__ __align__(16) unsigned pkS[KP*NROW];  // sech2 packed,    [kp][row], 4 KB
  __shared__ float sPart[2*NROW*DIM];              // k-half partials, 16 KB
  __shared__ float red[32];
  __shared__ float bcast[4];

  // ---- one-time: W -> interleaved packed f16 (normal + transposed) ----
  {
    int e  = b*NTHR + tid;                    // [0, 131072)
    int kp = e >> 9, c = e & 511;
    size_t qi = (size_t)(kp >> 2)*2048 + (size_t)c*4 + (kp & 3);
    Wq[qi] = packh(W[(size_t)(2*kp)*DIM + c], W[(size_t)(2*kp+1)*DIM + c]);
    float2 wt = *reinterpret_cast<const float2*>(W + (size_t)c*DIM + 2*kp);
    WTq[qi] = packh(wt.x, wt.y);
  }

  // per-thread persistent state: 2 elements of one batch row (pointwise layout)
  float x[2], bv[2];
  { float2 xx = *reinterpret_cast<const float2*>(x0 + (size_t)grow*DIM + colA);
    x[0]=xx.x; x[1]=xx.y; }
  { float2 b2 = *reinterpret_cast<const float2*>(bvec + colA);
    bv[0]=b2.x; bv[1]=b2.y; }

  grid.sync();   // publish Wq/WTq across XCDs (once)

  float t = 0.f, dt = DT0f;
  float k1[2],k2[2],k3[2],k4[2],k5[2],xhi[2],yreg[2];

  // matmul: a[r] = sum over this thread's k-half of  w2(kp,c) dot y2(kp,r); store to sPart
  auto mm_store = [&](const unsigned* __restrict__ Wp, const unsigned (&pk)[KP*NROW]){
    float a0=0.f, a1=0.f, a2=0.f, a3=0.f;
    const int kbase = mh * KHALF;
    const unsigned* wp = Wp + (size_t)(kbase >> 2)*2048 + (size_t)mc*4;
    #pragma unroll 4
    for (int kt = 0; kt < KHALF/4; ++kt){
      const int kp0 = kbase + kt*4;
      uint4 w  = *reinterpret_cast<const uint4*>(wp); wp += 2048;
      uint4 y0 = *reinterpret_cast<const uint4*>(&pk[(kp0+0)*NROW]);
      uint4 y1 = *reinterpret_cast<const uint4*>(&pk[(kp0+1)*NROW]);
      uint4 y2 = *reinterpret_cast<const uint4*>(&pk[(kp0+2)*NROW]);
      uint4 y3 = *reinterpret_cast<const uint4*>(&pk[(kp0+3)*NROW]);
      a0 = dot2f(w.x, y0.x, a0); a1 = dot2f(w.x, y0.y, a1); a2 = dot2f(w.x, y0.z, a2); a3 = dot2f(w.x, y0.w, a3);
      a0 = dot2f(w.y, y1.x, a0); a1 = dot2f(w.y, y1.y, a1); a2 = dot2f(w.y, y1.z, a2); a3 = dot2f(w.y, y1.w, a3);
      a0 = dot2f(w.z, y2.x, a0); a1 = dot2f(w.z, y2.y, a1); a2 = dot2f(w.z, y2.z, a2); a3 = dot2f(w.z, y2.w, a3);
      a0 = dot2f(w.w, y3.x, a0); a1 = dot2f(w.w, y3.y, a1); a2 = dot2f(w.w, y3.z, a2); a3 = dot2f(w.w, y3.w, a3);
    }
    sPart[(mh*NROW + 0)*DIM + mc] = a0;
    sPart[(mh*NROW + 1)*DIM + mc] = a1;
    sPart[(mh*NROW + 2)*DIM + mc] = a2;
    sPart[(mh*NROW + 3)*DIM + mc] = a3;
  };

  auto comb = [&](float g[2]){   // combine the two k-half partials (pointwise layout)
    float2 p0 = *reinterpret_cast<const float2*>(&sPart[(0*NROW + pr)*DIM + colA]);
    float2 p1 = *reinterpret_cast<const float2*>(&sPart[(1*NROW + pr)*DIM + colA]);
    g[0] = p0.x + p1.x; g[1] = p0.y + p1.y;
  };

  auto set_y = [&](float y0, float y1){
    yreg[0] = y0; yreg[1] = y1;
    pkY[pc*NROW + pr] = packh(y0, y1);
    __syncthreads();
  };
  auto run_fwd = [&](){
    mm_store(Wq, pkY);
    __syncthreads();
    float g[2]; comb(g);
    float th0 = tanhf(g[0] + bv[0]);
    float th1 = tanhf(g[1] + bv[1]);
    pkS[pc*NROW + pr] = packh(1.f - th0*th0, 1.f - th1*th1);
    __syncthreads();
  };
  auto run_bwd = [&](float ko[2]){
    mm_store(WTq, pkS);
    __syncthreads();
    float g[2]; comb(g);
    ko[0] = -(2.f*yreg[0] + g[0]) * INVD;
    ko[1] = -(2.f*yreg[1] + g[1]) * INVD;
  };

  for (int iter = 0; iter < 32; ++iter){
    // ---- 5 full stages ----
    set_y(x[0], x[1]);
    run_fwd(); run_bwd(k1);
    set_y(x[0]+dt*(cA21*k1[0]), x[1]+dt*(cA21*k1[1]));
    run_fwd(); run_bwd(k2);
    set_y(x[0]+dt*(cA31*k1[0]+cA32*k2[0]), x[1]+dt*(cA31*k1[1]+cA32*k2[1]));
    run_fwd(); run_bwd(k3);
    set_y(x[0]+dt*(cA41*k1[0]+cA42*k2[0]+cA43*k3[0]),
          x[1]+dt*(cA41*k1[1]+cA42*k2[1]+cA43*k3[1]));
    run_fwd(); run_bwd(k4);
    set_y(x[0]+dt*(cA51*k1[0]+cA52*k2[0]+cA53*k3[0]+cA54*k4[0]),
          x[1]+dt*(cA51*k1[1]+cA52*k2[1]+cA53*k3[1]+cA54*k4[1]));
    run_fwd(); run_bwd(k5);

    // ---- stage 6 fused: k6 / x_hi / x_lo / err ----
    set_y(x[0]+dt*(cA61*k1[0]+cA62*k2[0]+cA63*k3[0]+cA64*k4[0]+cA65*k5[0]),
          x[1]+dt*(cA61*k1[1]+cA62*k2[1]+cA63*k3[1]+cA64*k4[1]+cA65*k5[1]));
    run_fwd();
    mm_store(WTq, pkS);
    __syncthreads();
    {
      float g[2]; comb(g);
      float emax = 0.f;
      #pragma unroll
      for (int i = 0; i < 2; ++i){
        float k6 = -(2.f*yreg[i] + g[i]) * INVD;
        float hi = x[i] + dt*(cB1*k1[i] + cB3*k3[i] + cB4*k4[i] + cB5*k5[i] + cB6*k6);
        float lo = x[i] + dt*(cC1*k1[i] + cC3*k3[i] + cC4*k4[i] + cC5*k5[i]);
        xhi[i] = hi;
        emax = fmaxf(emax, fabsf(hi - lo));
      }
      #pragma unroll
      for (int s = 32; s > 0; s >>= 1) emax = fmaxf(emax, __shfl_xor(emax, s, 64));
      if (lane == 0) red[wid] = emax;
      __syncthreads();
      if (tid == 0){
        float m = red[0];
        #pragma unroll
        for (int wv = 1; wv < 16; ++wv) m = fmaxf(m, red[wv]);
        atomicMax(&errs[iter], __float_as_uint(m));
      }
    }

    gbar(&bar[2*iter], tid);                        // grid barrier #1
    if (tid == 0)
      bcast[0] = __uint_as_float(__hip_atomic_load(&errs[iter], __ATOMIC_RELAXED, __HIP_MEMORY_SCOPE_AGENT));
    __syncthreads();
    const float err = bcast[0];
    const bool accept = (err < TOLf) || (dt <= MIN_DTf);
    if (accept){ x[0]=xhi[0]; x[1]=xhi[1]; }

    // ---- stop condition: pvf(x2), per-row max |v|, grid mean over rows ----
    set_y(x[0], x[1]);
    run_fwd();
    mm_store(WTq, pkS);
    __syncthreads();
    {
      float g[2]; comb(g);
      float vmax = fmaxf(fabsf(-(2.f*x[0] + g[0]) * INVD),
                         fabsf(-(2.f*x[1] + g[1]) * INVD));
      #pragma unroll
      for (int s = 32; s > 0; s >>= 1) vmax = fmaxf(vmax, __shfl_xor(vmax, s, 64));
      if (lane == 0) red[wid] = vmax;               // 4 waves per row
      __syncthreads();
      if (tid == 0){
        double rsum = 0.0;
        #pragma unroll
        for (int rr = 0; rr < NROW; ++rr){
          float rm = fmaxf(fmaxf(red[4*rr], red[4*rr+1]), fmaxf(red[4*rr+2], red[4*rr+3]));
          rsum += (double)rm;
        }
        unsigned long long fx = (unsigned long long)(rsum * 4294967296.0);
        atomicAdd(&vels[iter], fx);
      }
    }

    gbar(&bar[2*iter+1], tid);                      // grid barrier #2
    if (tid == 0){
      unsigned long long sv = __hip_atomic_load(&vels[iter], __ATOMIC_RELAXED, __HIP_MEMORY_SCOPE_AGENT);
      float vel = (float)((double)sv * (1.0/4294967296.0) / 512.0);
      float t2  = accept ? (t + dt) : t;
      float factor = 0.9f * powf(TOLf / (err + 1e-12f), 0.2f);
      factor = fminf(fmaxf(factor, 0.2f), 2.0f);
      float dtn = fmaxf(dt * factor, MIN_DTf);
      bcast[0] = t2; bcast[1] = dtn;
      bcast[2] = ((t2 > MAXTf) || (vel < VELTOLf)) ? 1.f : 0.f;
    }
    __syncthreads();
    t = bcast[0]; dt = bcast[1];
    if (bcast[2] != 0.f) break;                     // uniform across grid
  }

  float2 o; o.x = x[0]; o.y = x[1];
  *reinterpret_cast<float2*>(out + (size_t)grow*DIM + colA) = o;
}

extern "C" void kernel_launch(void* const* d_in, const int* in_sizes, int n_in,
                              void* d_out, int out_size, void* d_ws, size_t ws_size,
                              hipStream_t stream)
{
  const float* x0 = (const float*)d_in[0];
  const float* W  = (const float*)d_in[1];
  const float* bv = (const float*)d_in[2];
  float* out = (float*)d_out;
  unsigned char* ws = (unsigned char*)d_ws;

  hipMemsetAsync(ws, 0, 4096, stream);   // barrier slots + errs + vels

  void* args[] = { (void*)&x0, (void*)&W, (void*)&bv, (void*)&out, (void*)&ws };
  (void)in_sizes; (void)n_in; (void)out_size; (void)ws_size;
  hipLaunchCooperativeKernel((void*)hop_kernel, dim3(NBLK), dim3(NTHR), args, 0, stream);
}